// Round 1
// baseline (419.266 us; speedup 1.0000x reference)
//
#include <hip/hip_runtime.h>
#include <cstdint>
#include <cstddef>

#define L_ 2048
#define D_ 128
#define B_ 32

static constexpr float SCALE = 0.08838834764831845f;  // 1/sqrt(128)
static constexpr float LOG2E = 1.4426950408889634f;

typedef __bf16 bf16x8 __attribute__((ext_vector_type(8)));
typedef __bf16 bf16x4 __attribute__((ext_vector_type(4)));
typedef float  f32x4  __attribute__((ext_vector_type(4)));

// ---------------------------------------------------------------------------
// Kernel 1: flash attention (online softmax), bf16 MFMA 16x16x32.
//   grid = (B=32, L/64=32), block = 256 (4 waves).
//   Each wave owns 16 q-rows; block stages K-tile (64x128) and V^T-tile
//   (128x64) in swizzled bf16 LDS.
//   For b==0, raw scaled scores are dumped to attn0 (normalized by kernel 2).
// ---------------------------------------------------------------------------
__global__ __launch_bounds__(256) void attn_fwd(
    const float* __restrict__ Q, const float* __restrict__ K,
    const float* __restrict__ V, const float* __restrict__ bias,
    float* __restrict__ ctx, float* __restrict__ attn0)
{
  const int b    = blockIdx.x;
  const int qblk = blockIdx.y;
  const int tid  = threadIdx.x;
  const int wave = tid >> 6;
  const int lane = tid & 63;
  const int lg   = lane >> 4;   // 0..3
  const int lr   = lane & 15;   // 0..15

  const int qbase = qblk * 64 + wave * 16;

  __shared__ alignas(16) __bf16 Ksh[64 * 128];    // K tile, swizzled
  __shared__ alignas(16) __bf16 Vtsh[128 * 64];   // V^T tile, swizzled
  __shared__ alignas(16) __bf16 Psh[4][16 * 72];  // per-wave P, padded stride

  char* const kb = (char*)Ksh;
  char* const vb = (char*)Vtsh;

  // ---- Q fragments (A operand): lane holds Q[qbase+lr][kc*32 + lg*8 + j] ----
  bf16x8 qf[4];
  {
    const float* qrow = Q + ((size_t)b * L_ + (qbase + lr)) * D_;
#pragma unroll
    for (int kc = 0; kc < 4; ++kc) {
      const int d0 = kc * 32 + lg * 8;
      float4 a = *(const float4*)(qrow + d0);
      float4 c = *(const float4*)(qrow + d0 + 4);
      bf16x8 f;
      f[0] = (__bf16)a.x; f[1] = (__bf16)a.y; f[2] = (__bf16)a.z; f[3] = (__bf16)a.w;
      f[4] = (__bf16)c.x; f[5] = (__bf16)c.y; f[6] = (__bf16)c.z; f[7] = (__bf16)c.w;
      qf[kc] = f;
    }
  }

  f32x4 Oacc[8];
#pragma unroll
  for (int i = 0; i < 8; ++i) Oacc[i] = (f32x4){0.f, 0.f, 0.f, 0.f};
  float m_run[4] = {-3.0e38f, -3.0e38f, -3.0e38f, -3.0e38f};
  float l_run[4] = {0.f, 0.f, 0.f, 0.f};

  for (int kt = 0; kt < L_ / 64; ++kt) {
    const int kvbase = kt * 64;

    // ---- stage K (bf16, swizzled) and V^T (bf16, swizzled) ----
#pragma unroll
    for (int it = 0; it < 8; ++it) {
      const int g  = tid + it * 256;   // float4 group id, 0..2047
      const int r  = g >> 5;           // kv row 0..63
      const int d0 = (g & 31) * 4;     // 0..124
      const size_t src = ((size_t)b * L_ + (kvbase + r)) * D_ + d0;
      float4 kv4 = *(const float4*)(K + src);
      bf16x4 k4 = {(__bf16)kv4.x, (__bf16)kv4.y, (__bf16)kv4.z, (__bf16)kv4.w};
      *(bf16x4*)(kb + r * 256 + ((d0 * 2) ^ ((r & 7) << 4))) = k4;

      float4 vv4 = *(const float4*)(V + src);
      float vvv[4] = {vv4.x, vv4.y, vv4.z, vv4.w};
#pragma unroll
      for (int jj = 0; jj < 4; ++jj) {
        const int d = d0 + jj;
        *(__bf16*)(vb + d * 128 + ((r * 2) ^ ((d & 7) << 4))) = (__bf16)vvv[jj];
      }
    }
    __syncthreads();

    // ---- S = Q . K^T  (16x64 per wave) ----
    f32x4 Sacc[4];
#pragma unroll
    for (int t = 0; t < 4; ++t) Sacc[t] = (f32x4){0.f, 0.f, 0.f, 0.f};
#pragma unroll
    for (int t = 0; t < 4; ++t) {
      const int r   = t * 16 + lr;
      const int swz = (r & 7) << 4;
#pragma unroll
      for (int kc = 0; kc < 4; ++kc) {
        const int d0 = kc * 32 + lg * 8;
        bf16x8 kf = *(const bf16x8*)(kb + r * 256 + ((d0 * 2) ^ swz));
        Sacc[t] = __builtin_amdgcn_mfma_f32_16x16x32_bf16(qf[kc], kf, Sacc[t], 0, 0, 0);
      }
    }

    // ---- z = (S + bias) * SCALE  (C/D layout: row = lg*4+j, col = t*16+lr) ----
    float z[4][4];
    const int qr = qbase + lg * 4;
#pragma unroll
    for (int t = 0; t < 4; ++t) {
      const int kcol = kvbase + t * 16 + lr;
#pragma unroll
      for (int j = 0; j < 4; ++j)
        z[t][j] = (Sacc[t][j] + bias[(size_t)(qr + j) * L_ + kcol]) * SCALE;
    }
    if (b == 0) {
#pragma unroll
      for (int t = 0; t < 4; ++t) {
        const int kcol = kvbase + t * 16 + lr;
#pragma unroll
        for (int j = 0; j < 4; ++j)
          attn0[(size_t)(qr + j) * L_ + kcol] = z[t][j];
      }
    }

    // ---- online softmax (per q-row; 16-lane butterfly over the 64 cols) ----
    float mt[4], corr[4], rs[4];
#pragma unroll
    for (int j = 0; j < 4; ++j) {
      float mm = fmaxf(fmaxf(z[0][j], z[1][j]), fmaxf(z[2][j], z[3][j]));
#pragma unroll
      for (int msk = 1; msk < 16; msk <<= 1) mm = fmaxf(mm, __shfl_xor(mm, msk));
      mt[j] = mm;
    }
#pragma unroll
    for (int j = 0; j < 4; ++j) {
      const float mnew = fmaxf(m_run[j], mt[j]);
      corr[j]  = exp2f((m_run[j] - mnew) * LOG2E);
      m_run[j] = mnew;
      rs[j]    = 0.f;
    }
    __bf16 pb[4][4];
#pragma unroll
    for (int t = 0; t < 4; ++t)
#pragma unroll
      for (int j = 0; j < 4; ++j) {
        const float p = exp2f((z[t][j] - m_run[j]) * LOG2E);
        rs[j] += p;
        pb[t][j] = (__bf16)p;
      }
#pragma unroll
    for (int j = 0; j < 4; ++j) {
      float s = rs[j];
#pragma unroll
      for (int msk = 1; msk < 16; msk <<= 1) s += __shfl_xor(s, msk);
      l_run[j] = l_run[j] * corr[j] + s;
    }
#pragma unroll
    for (int dt = 0; dt < 8; ++dt)
#pragma unroll
      for (int j = 0; j < 4; ++j) Oacc[dt][j] *= corr[j];

    // ---- P -> per-wave LDS (C-layout to A-fragment layout) ----
    __bf16* pw = &Psh[wave][0];
#pragma unroll
    for (int t = 0; t < 4; ++t)
#pragma unroll
      for (int j = 0; j < 4; ++j)
        pw[(lg * 4 + j) * 72 + t * 16 + lr] = pb[t][j];

    // ---- O += P . V ----
#pragma unroll
    for (int kc2 = 0; kc2 < 2; ++kc2) {
      bf16x8 pa = *(const bf16x8*)(pw + lr * 72 + kc2 * 32 + lg * 8);
      const int c0 = kc2 * 32 + lg * 8;
#pragma unroll
      for (int dt = 0; dt < 8; ++dt) {
        const int d = dt * 16 + lr;
        bf16x8 vf = *(const bf16x8*)(vb + d * 128 + ((c0 * 2) ^ ((d & 7) << 4)));
        Oacc[dt] = __builtin_amdgcn_mfma_f32_16x16x32_bf16(pa, vf, Oacc[dt], 0, 0, 0);
      }
    }
    __syncthreads();
  }

  // ---- epilogue: ctx = O / l ----
  float inv[4];
#pragma unroll
  for (int j = 0; j < 4; ++j) inv[j] = 1.f / l_run[j];
#pragma unroll
  for (int dt = 0; dt < 8; ++dt) {
    const int d = dt * 16 + lr;
#pragma unroll
    for (int j = 0; j < 4; ++j) {
      const int q = qbase + lg * 4 + j;
      ctx[((size_t)b * L_ + q) * D_ + d] = Oacc[dt][j] * inv[j];
    }
  }
}

// ---------------------------------------------------------------------------
// Kernel 2: in-place row softmax of attn0 (raw scaled scores for batch 0).
//   grid = 2048 rows, block = 256; 8 elems/thread.
// ---------------------------------------------------------------------------
__global__ __launch_bounds__(256) void softmax_rows(float* __restrict__ attn0)
{
  const int row  = blockIdx.x;
  float* p = attn0 + (size_t)row * L_;
  const int tid  = threadIdx.x;
  const int wave = tid >> 6;
  const int lane = tid & 63;
  __shared__ float red[8];

  float4 a = ((const float4*)p)[tid];
  float4 c = ((const float4*)p)[tid + 256];
  float v[8] = {a.x, a.y, a.z, a.w, c.x, c.y, c.z, c.w};

  float mx = v[0];
#pragma unroll
  for (int i = 1; i < 8; ++i) mx = fmaxf(mx, v[i]);
#pragma unroll
  for (int msk = 1; msk < 64; msk <<= 1) mx = fmaxf(mx, __shfl_xor(mx, msk));
  if (lane == 0) red[wave] = mx;
  __syncthreads();
  mx = fmaxf(fmaxf(red[0], red[1]), fmaxf(red[2], red[3]));

  float e[8];
  float s = 0.f;
#pragma unroll
  for (int i = 0; i < 8; ++i) { e[i] = exp2f((v[i] - mx) * LOG2E); s += e[i]; }
#pragma unroll
  for (int msk = 1; msk < 64; msk <<= 1) s += __shfl_xor(s, msk);
  if (lane == 0) red[4 + wave] = s;
  __syncthreads();
  s = red[4] + red[5] + red[6] + red[7];
  const float inv = 1.f / s;

  float4 o0 = {e[0] * inv, e[1] * inv, e[2] * inv, e[3] * inv};
  float4 o1 = {e[4] * inv, e[5] * inv, e[6] * inv, e[7] * inv};
  ((float4*)p)[tid]       = o0;
  ((float4*)p)[tid + 256] = o1;
}

extern "C" void kernel_launch(void* const* d_in, const int* in_sizes, int n_in,
                              void* d_out, int out_size, void* d_ws, size_t ws_size,
                              hipStream_t stream) {
  const float* Q    = (const float*)d_in[0];
  const float* K    = (const float*)d_in[1];
  const float* V    = (const float*)d_in[2];
  const float* bias = (const float*)d_in[3];
  float* ctx   = (float*)d_out;
  float* attn0 = ctx + (size_t)B_ * L_ * D_;

  dim3 grid(B_, L_ / 64);  // batch fastest -> bias rows L2-shared across batches
  attn_fwd<<<grid, 256, 0, stream>>>(Q, K, V, bias, ctx, attn0);
  softmax_rows<<<L_, 256, 0, stream>>>(attn0);
}

// Round 2
// 285.165 us; speedup vs baseline: 1.4703x; 1.4703x over previous
//
#include <hip/hip_runtime.h>
#include <cstdint>
#include <cstddef>

#define L_ 2048
#define D_ 128
#define B_ 32

static constexpr float SCALE = 0.08838834764831845f;  // 1/sqrt(128)
static constexpr float LOG2E = 1.4426950408889634f;

typedef __bf16 bf16x8 __attribute__((ext_vector_type(8)));
typedef __bf16 bf16x4 __attribute__((ext_vector_type(4)));
typedef float  f32x4  __attribute__((ext_vector_type(4)));

// ---------------------------------------------------------------------------
// Kernel 1: flash attention (online softmax), bf16 MFMA 16x16x32.
//   1D grid 1024 (XCD-swizzled -> (b, qblk)), block = 256 (4 waves).
//   Each wave owns 16 q-rows; block stages K-tile (64x128) and V^T-tile
//   (128x64) in swizzled bf16 LDS. LDS total = 40960 B -> 4 blocks/CU.
//   V^T staging: lane = kv row, wave = d-chunk -> transpose writes hit one
//   contiguous 128B LDS row per step (conflict-free; was 16-way, 1.35e8 cyc).
//   For b==0, raw scaled scores are dumped to attn0 (normalized by kernel 2).
// ---------------------------------------------------------------------------
__global__ __launch_bounds__(256) void attn_fwd(
    const float* __restrict__ Q, const float* __restrict__ K,
    const float* __restrict__ V, const float* __restrict__ bias,
    float* __restrict__ ctx, float* __restrict__ attn0)
{
  // XCD-aware swizzle: XCD x gets batches 4x..4x+3, all 32 qblks.
  const int id   = blockIdx.x;
  const int xcd  = id & 7;
  const int idx  = id >> 3;
  const int b    = xcd * 4 + (idx >> 5);
  const int qblk = idx & 31;

  const int tid  = threadIdx.x;
  const int wave = tid >> 6;
  const int lane = tid & 63;
  const int lg   = lane >> 4;   // 0..3
  const int lr   = lane & 15;   // 0..15

  const int qbase = qblk * 64 + wave * 16;

  __shared__ alignas(16) __bf16 Ksh[64 * 128];    // K tile, swizzled (16 KiB)
  __shared__ alignas(16) __bf16 Vtsh[128 * 64];   // V^T tile, swizzled (16 KiB)
  __shared__ alignas(16) __bf16 Psh[4][16 * 64];  // per-wave P, XOR-swizzled (8 KiB)

  char* const kb = (char*)Ksh;
  char* const vb = (char*)Vtsh;

  // ---- Q fragments (A operand): lane holds Q[qbase+lr][kc*32 + lg*8 + j] ----
  bf16x8 qf[4];
  {
    const float* qrow = Q + ((size_t)b * L_ + (qbase + lr)) * D_;
#pragma unroll
    for (int kc = 0; kc < 4; ++kc) {
      const int d0 = kc * 32 + lg * 8;
      float4 a = *(const float4*)(qrow + d0);
      float4 c = *(const float4*)(qrow + d0 + 4);
      bf16x8 f;
      f[0] = (__bf16)a.x; f[1] = (__bf16)a.y; f[2] = (__bf16)a.z; f[3] = (__bf16)a.w;
      f[4] = (__bf16)c.x; f[5] = (__bf16)c.y; f[6] = (__bf16)c.z; f[7] = (__bf16)c.w;
      qf[kc] = f;
    }
  }

  // V staging mapping: lane = kv row, wave picks 32-wide d chunk.
  const int vr = lane;           // kv row 0..63
  const int vdbase = wave * 32;  // d chunk

  f32x4 Oacc[8];
#pragma unroll
  for (int i = 0; i < 8; ++i) Oacc[i] = (f32x4){0.f, 0.f, 0.f, 0.f};
  float m_run[4] = {-3.0e38f, -3.0e38f, -3.0e38f, -3.0e38f};
  float l_run[4] = {0.f, 0.f, 0.f, 0.f};

  for (int kt = 0; kt < L_ / 64; ++kt) {
    const int kvbase = kt * 64;

    // ---- stage K (bf16, swizzled rows) ----
#pragma unroll
    for (int it = 0; it < 8; ++it) {
      const int g  = tid + it * 256;   // float4 group id, 0..2047
      const int r  = g >> 5;           // kv row 0..63
      const int d0 = (g & 31) * 4;     // 0..124
      const size_t src = ((size_t)b * L_ + (kvbase + r)) * D_ + d0;
      float4 kv4 = *(const float4*)(K + src);
      bf16x4 k4 = {(__bf16)kv4.x, (__bf16)kv4.y, (__bf16)kv4.z, (__bf16)kv4.w};
      *(bf16x4*)(kb + r * 256 + ((d0 * 2) ^ ((r & 7) << 4)));
      *(bf16x4*)(kb + r * 256 + ((d0 * 2) ^ ((r & 7) << 4))) = k4;
    }

    // ---- stage V^T (lane = row -> conflict-free transpose writes) ----
    {
      const float* vrow = V + ((size_t)b * L_ + (kvbase + vr)) * D_ + vdbase;
#pragma unroll
      for (int c = 0; c < 8; ++c) {
        float4 v4 = *(const float4*)(vrow + c * 4);
        const int d0 = vdbase + c * 4;
        float vv[4] = {v4.x, v4.y, v4.z, v4.w};
#pragma unroll
        for (int jj = 0; jj < 4; ++jj) {
          const int d = d0 + jj;
          *(__bf16*)(vb + d * 128 + ((vr * 2) ^ ((d & 7) << 4))) = (__bf16)vv[jj];
        }
      }
    }
    __syncthreads();

    // ---- S = Q . K^T  (16x64 per wave) ----
    f32x4 Sacc[4];
#pragma unroll
    for (int t = 0; t < 4; ++t) Sacc[t] = (f32x4){0.f, 0.f, 0.f, 0.f};
#pragma unroll
    for (int t = 0; t < 4; ++t) {
      const int r   = t * 16 + lr;
      const int swz = (r & 7) << 4;
#pragma unroll
      for (int kc = 0; kc < 4; ++kc) {
        const int d0 = kc * 32 + lg * 8;
        bf16x8 kf = *(const bf16x8*)(kb + r * 256 + ((d0 * 2) ^ swz));
        Sacc[t] = __builtin_amdgcn_mfma_f32_16x16x32_bf16(qf[kc], kf, Sacc[t], 0, 0, 0);
      }
    }

    // ---- z = (S + bias) * SCALE  (C/D layout: row = lg*4+j, col = t*16+lr) ----
    float z[4][4];
    const int qr = qbase + lg * 4;
#pragma unroll
    for (int t = 0; t < 4; ++t) {
      const int kcol = kvbase + t * 16 + lr;
#pragma unroll
      for (int j = 0; j < 4; ++j)
        z[t][j] = (Sacc[t][j] + bias[(size_t)(qr + j) * L_ + kcol]) * SCALE;
    }
    if (b == 0) {
#pragma unroll
      for (int t = 0; t < 4; ++t) {
        const int kcol = kvbase + t * 16 + lr;
#pragma unroll
        for (int j = 0; j < 4; ++j)
          attn0[(size_t)(qr + j) * L_ + kcol] = z[t][j];
      }
    }

    // ---- online softmax (per q-row; 16-lane butterfly over the 64 cols) ----
    float mt[4], corr[4], rs[4];
#pragma unroll
    for (int j = 0; j < 4; ++j) {
      float mm = fmaxf(fmaxf(z[0][j], z[1][j]), fmaxf(z[2][j], z[3][j]));
#pragma unroll
      for (int msk = 1; msk < 16; msk <<= 1) mm = fmaxf(mm, __shfl_xor(mm, msk));
      mt[j] = mm;
    }
#pragma unroll
    for (int j = 0; j < 4; ++j) {
      const float mnew = fmaxf(m_run[j], mt[j]);
      corr[j]  = exp2f((m_run[j] - mnew) * LOG2E);
      m_run[j] = mnew;
      rs[j]    = 0.f;
    }
    __bf16 pb[4][4];
#pragma unroll
    for (int t = 0; t < 4; ++t)
#pragma unroll
      for (int j = 0; j < 4; ++j) {
        const float p = exp2f((z[t][j] - m_run[j]) * LOG2E);
        rs[j] += p;
        pb[t][j] = (__bf16)p;
      }
#pragma unroll
    for (int j = 0; j < 4; ++j) {
      float s = rs[j];
#pragma unroll
      for (int msk = 1; msk < 16; msk <<= 1) s += __shfl_xor(s, msk);
      l_run[j] = l_run[j] * corr[j] + s;
    }
#pragma unroll
    for (int dt = 0; dt < 8; ++dt)
#pragma unroll
      for (int j = 0; j < 4; ++j) Oacc[dt][j] *= corr[j];

    // ---- P -> per-wave LDS (C-layout to A-fragment layout), XOR-swizzled ----
    // element (m, c) at byte m*128 + ((c ^ (((m>>2)&3)<<4)) * 2)
    __bf16* pw = &Psh[wave][0];
    {
      const int m = lg * 4;  // + j
#pragma unroll
      for (int j = 0; j < 4; ++j) {
        const int s = lg << 4;  // ((m+j)>>2)&3 == lg
#pragma unroll
        for (int t = 0; t < 4; ++t) {
          const int c = t * 16 + lr;
          pw[(m + j) * 64 + (c ^ s)] = pb[t][j];
        }
      }
    }

    // ---- O += P . V ----
#pragma unroll
    for (int kc2 = 0; kc2 < 2; ++kc2) {
      const int c0 = kc2 * 32 + lg * 8;
      const int rs2 = ((lr >> 2) & 3) << 4;
      bf16x8 pa = *(const bf16x8*)(pw + lr * 64 + (c0 ^ rs2));
#pragma unroll
      for (int dt = 0; dt < 8; ++dt) {
        const int d = dt * 16 + lr;
        bf16x8 vf = *(const bf16x8*)(vb + d * 128 + (((kc2 * 32 + lg * 8) * 2) ^ ((d & 7) << 4)));
        Oacc[dt] = __builtin_amdgcn_mfma_f32_16x16x32_bf16(pa, vf, Oacc[dt], 0, 0, 0);
      }
    }
    __syncthreads();
  }

  // ---- epilogue: ctx = O / l ----
  float inv[4];
#pragma unroll
  for (int j = 0; j < 4; ++j) inv[j] = 1.f / l_run[j];
#pragma unroll
  for (int dt = 0; dt < 8; ++dt) {
    const int d = dt * 16 + lr;
#pragma unroll
    for (int j = 0; j < 4; ++j) {
      const int q = qbase + lg * 4 + j;
      ctx[((size_t)b * L_ + q) * D_ + d] = Oacc[dt][j] * inv[j];
    }
  }
}

// ---------------------------------------------------------------------------
// Kernel 2: in-place row softmax of attn0 (raw scaled scores for batch 0).
//   grid = 2048 rows, block = 256; 8 elems/thread.
// ---------------------------------------------------------------------------
__global__ __launch_bounds__(256) void softmax_rows(float* __restrict__ attn0)
{
  const int row  = blockIdx.x;
  float* p = attn0 + (size_t)row * L_;
  const int tid  = threadIdx.x;
  const int wave = tid >> 6;
  const int lane = tid & 63;
  __shared__ float red[8];

  float4 a = ((const float4*)p)[tid];
  float4 c = ((const float4*)p)[tid + 256];
  float v[8] = {a.x, a.y, a.z, a.w, c.x, c.y, c.z, c.w};

  float mx = v[0];
#pragma unroll
  for (int i = 1; i < 8; ++i) mx = fmaxf(mx, v[i]);
#pragma unroll
  for (int msk = 1; msk < 64; msk <<= 1) mx = fmaxf(mx, __shfl_xor(mx, msk));
  if (lane == 0) red[wave] = mx;
  __syncthreads();
  mx = fmaxf(fmaxf(red[0], red[1]), fmaxf(red[2], red[3]));

  float e[8];
  float s = 0.f;
#pragma unroll
  for (int i = 0; i < 8; ++i) { e[i] = exp2f((v[i] - mx) * LOG2E); s += e[i]; }
#pragma unroll
  for (int msk = 1; msk < 64; msk <<= 1) s += __shfl_xor(s, msk);
  if (lane == 0) red[4 + wave] = s;
  __syncthreads();
  s = red[4] + red[5] + red[6] + red[7];
  const float inv = 1.f / s;

  float4 o0 = {e[0] * inv, e[1] * inv, e[2] * inv, e[3] * inv};
  float4 o1 = {e[4] * inv, e[5] * inv, e[6] * inv, e[7] * inv};
  ((float4*)p)[tid]       = o0;
  ((float4*)p)[tid + 256] = o1;
}

extern "C" void kernel_launch(void* const* d_in, const int* in_sizes, int n_in,
                              void* d_out, int out_size, void* d_ws, size_t ws_size,
                              hipStream_t stream) {
  const float* Q    = (const float*)d_in[0];
  const float* K    = (const float*)d_in[1];
  const float* V    = (const float*)d_in[2];
  const float* bias = (const float*)d_in[3];
  float* ctx   = (float*)d_out;
  float* attn0 = ctx + (size_t)B_ * L_ * D_;

  attn_fwd<<<dim3(B_ * (L_ / 64)), 256, 0, stream>>>(Q, K, V, bias, ctx, attn0);
  softmax_rows<<<L_, 256, 0, stream>>>(attn0);
}

// Round 3
// 221.496 us; speedup vs baseline: 1.8929x; 1.2875x over previous
//
#include <hip/hip_runtime.h>
#include <cstdint>
#include <cstddef>

#define L_ 2048
#define D_ 128
#define B_ 32
#define NT_ 32   // kv tiles of 64

static constexpr float SCALE = 0.08838834764831845f;  // 1/sqrt(128)
static constexpr float LOG2E = 1.4426950408889634f;

typedef __bf16 bf16x8 __attribute__((ext_vector_type(8)));
typedef __bf16 bf16x4 __attribute__((ext_vector_type(4)));
typedef float  f32x4  __attribute__((ext_vector_type(4)));
typedef int    i32x4  __attribute__((ext_vector_type(4)));

typedef const __attribute__((address_space(1))) uint32_t* gas_t;
typedef __attribute__((address_space(3))) uint32_t*       las_t;

__device__ __forceinline__ void dma16(const void* g, void* l) {
  // lds dest is wave-uniform base; HW adds lane*16. size must be literal 16.
  __builtin_amdgcn_global_load_lds((gas_t)g, (las_t)l, 16, 0, 0);
}

// ---------------------------------------------------------------------------
// prep_kv: once per (batch, kv-tile):
//   gK : bf16 K-tile image, chunk-permuted so a LINEAR 16KB DMA into LDS
//        reproduces the XOR-swizzled layout attn reads (chunk c holds
//        K[r][8*(c^(r&7))..+8] at byte r*256 + c*16).
//   gVt: bf16 V^T-tile image (transposed + swizzled), built via LDS with the
//        conflict-free lane=kv-row mapping, dumped linearly.
// grid = B*NT = 1024 blocks, 256 threads.
// ---------------------------------------------------------------------------
__global__ __launch_bounds__(256) void prep_kv(
    const float* __restrict__ K, const float* __restrict__ V,
    __bf16* __restrict__ gK, __bf16* __restrict__ gVt)
{
  const int b   = blockIdx.x >> 5;
  const int kt  = blockIdx.x & 31;
  const int tid = threadIdx.x;
  const size_t tile = ((size_t)b * NT_ + kt) * 8192;  // bf16 elems per tile

  // ---- K: direct permuted write (16B chunks stay intact) ----
#pragma unroll
  for (int i = 0; i < 4; ++i) {
    const int g  = tid + i * 256;   // chunk id 0..1023
    const int r  = g >> 4;          // kv row
    const int c  = g & 15;          // chunk within row
    const int d0 = (c ^ (r & 7)) * 8;
    const float* src = K + ((size_t)b * L_ + kt * 64 + r) * D_ + d0;
    float4 a = *(const float4*)src;
    float4 e = *(const float4*)(src + 4);
    bf16x8 f;
    f[0]=(__bf16)a.x; f[1]=(__bf16)a.y; f[2]=(__bf16)a.z; f[3]=(__bf16)a.w;
    f[4]=(__bf16)e.x; f[5]=(__bf16)e.y; f[6]=(__bf16)e.z; f[7]=(__bf16)e.w;
    *(bf16x8*)((char*)(gK + tile) + r * 256 + c * 16) = f;
  }

  // ---- V^T: swizzled image in LDS, then linear dump ----
  __shared__ alignas(16) __bf16 Vt[8192];
  char* vb = (char*)Vt;
  const int vr     = tid & 63;        // kv row (lanes vary row -> no conflict)
  const int vdbase = (tid >> 6) * 32; // d chunk per wave
  const float* vrow = V + ((size_t)b * L_ + kt * 64 + vr) * D_ + vdbase;
#pragma unroll
  for (int c = 0; c < 8; ++c) {
    float4 v4 = *(const float4*)(vrow + c * 4);
    const int d0 = vdbase + c * 4;
    float vv[4] = {v4.x, v4.y, v4.z, v4.w};
#pragma unroll
    for (int jj = 0; jj < 4; ++jj) {
      const int d = d0 + jj;
      *(__bf16*)(vb + d * 128 + ((vr * 2) ^ ((d & 7) << 4))) = (__bf16)vv[jj];
    }
  }
  __syncthreads();
#pragma unroll
  for (int i = 0; i < 4; ++i) {
    const int off = (tid + i * 256) * 16;
    *(i32x4*)((char*)(gVt + tile) + off) = *(const i32x4*)(vb + off);
  }
}

// ---------------------------------------------------------------------------
// attn_fwd<DMA>: flash attention, bf16 MFMA 16x16x32.
//   DMA=1: stage K/V tiles from prepped bf16 images via global_load_lds into
//          double-buffered LDS (72KB total); counted vmcnt(8), never 0 in loop.
//   DMA=0: fallback = round-2 in-kernel staging (single buffer).
//   grid 1024 (XCD-swizzled -> (b,qblk)), 256 threads (4 waves x 16 q-rows).
// ---------------------------------------------------------------------------
template<int DMA>
__global__ __launch_bounds__(256) void attn_fwd(
    const float* __restrict__ Q, const float* __restrict__ K,
    const float* __restrict__ V, const float* __restrict__ bias,
    const __bf16* __restrict__ gK, const __bf16* __restrict__ gVt,
    float* __restrict__ ctx, float* __restrict__ attn0)
{
  const int id   = blockIdx.x;
  const int xcd  = id & 7;
  const int idx  = id >> 3;
  const int b    = xcd * 4 + (idx >> 5);
  const int qblk = idx & 31;

  const int tid  = threadIdx.x;
  const int wave = tid >> 6;
  const int lane = tid & 63;
  const int lg   = lane >> 4;   // 0..3
  const int lr   = lane & 15;   // 0..15

  const int qbase = qblk * 64 + wave * 16;

  __shared__ alignas(16) __bf16 Ksh[(DMA ? 2 : 1) * 8192];
  __shared__ alignas(16) __bf16 Vtsh[(DMA ? 2 : 1) * 8192];
  __shared__ alignas(16) __bf16 Psh[4][16 * 64];

  // ---- Q fragments: lane holds Q[qbase+lr][kc*32 + lg*8 + j] ----
  bf16x8 qf[4];
  {
    const float* qrow = Q + ((size_t)b * L_ + (qbase + lr)) * D_;
#pragma unroll
    for (int kc = 0; kc < 4; ++kc) {
      const int d0 = kc * 32 + lg * 8;
      float4 a = *(const float4*)(qrow + d0);
      float4 c = *(const float4*)(qrow + d0 + 4);
      bf16x8 f;
      f[0] = (__bf16)a.x; f[1] = (__bf16)a.y; f[2] = (__bf16)a.z; f[3] = (__bf16)a.w;
      f[4] = (__bf16)c.x; f[5] = (__bf16)c.y; f[6] = (__bf16)c.z; f[7] = (__bf16)c.w;
      qf[kc] = f;
    }
  }

  f32x4 Oacc[8];
#pragma unroll
  for (int i = 0; i < 8; ++i) Oacc[i] = (f32x4){0.f, 0.f, 0.f, 0.f};
  float m_run[4] = {-3.0e38f, -3.0e38f, -3.0e38f, -3.0e38f};
  float l_run[4] = {0.f, 0.f, 0.f, 0.f};

  // DMA staging: 4 K-chunks + 4 V-chunks of 1KB per wave = 8 vmem instrs/thread.
  auto stage_dma = [&](int kt, int bufsel) {
    const char* gk = (const char*)(gK + ((size_t)b * NT_ + kt) * 8192);
    const char* gv = (const char*)(gVt + ((size_t)b * NT_ + kt) * 8192);
    char* kdst = (char*)Ksh + bufsel * 16384;
    char* vdst = (char*)Vtsh + bufsel * 16384;
#pragma unroll
    for (int i = 0; i < 4; ++i) {
      const int off  = (wave * 4 + i) * 1024;
      dma16(gk + off + lane * 16, kdst + off);
      dma16(gv + off + lane * 16, vdst + off);
    }
  };

  if constexpr (DMA) { stage_dma(0, 0); stage_dma(1, 1); }

  for (int kt = 0; kt < NT_; ++kt) {
    const int kvbase = kt * 64;
    const int cur = kt & 1;
    const char* kb;
    const char* vb;

    if constexpr (DMA) {
      kb = (const char*)Ksh + cur * 16384;
      vb = (const char*)Vtsh + cur * 16384;
      asm volatile("s_waitcnt vmcnt(8)" ::: "memory");
      __syncthreads();
    } else {
      kb = (const char*)Ksh;
      vb = (const char*)Vtsh;
      // ---- in-kernel staging (round-2 path) ----
#pragma unroll
      for (int it = 0; it < 8; ++it) {
        const int g  = tid + it * 256;
        const int r  = g >> 5;
        const int d0 = (g & 31) * 4;
        const size_t src = ((size_t)b * L_ + (kvbase + r)) * D_ + d0;
        float4 kv4 = *(const float4*)(K + src);
        bf16x4 k4 = {(__bf16)kv4.x, (__bf16)kv4.y, (__bf16)kv4.z, (__bf16)kv4.w};
        *(bf16x4*)((char*)Ksh + r * 256 + ((d0 * 2) ^ ((r & 7) << 4))) = k4;
      }
      {
        const int vr = lane;
        const int vdbase = wave * 32;
        const float* vrow = V + ((size_t)b * L_ + (kvbase + vr)) * D_ + vdbase;
#pragma unroll
        for (int c = 0; c < 8; ++c) {
          float4 v4 = *(const float4*)(vrow + c * 4);
          const int d0 = vdbase + c * 4;
          float vv[4] = {v4.x, v4.y, v4.z, v4.w};
#pragma unroll
          for (int jj = 0; jj < 4; ++jj) {
            const int d = d0 + jj;
            *(__bf16*)((char*)Vtsh + d * 128 + ((vr * 2) ^ ((d & 7) << 4))) = (__bf16)vv[jj];
          }
        }
      }
      __syncthreads();
    }

    // ---- S = Q . K^T (16x64 per wave) ----
    f32x4 Sacc[4];
#pragma unroll
    for (int t = 0; t < 4; ++t) Sacc[t] = (f32x4){0.f, 0.f, 0.f, 0.f};
#pragma unroll
    for (int t = 0; t < 4; ++t) {
      const int r   = t * 16 + lr;
      const int swz = (r & 7) << 4;
#pragma unroll
      for (int kc = 0; kc < 4; ++kc) {
        const int d0 = kc * 32 + lg * 8;
        bf16x8 kf = *(const bf16x8*)(kb + r * 256 + ((d0 * 2) ^ swz));
        Sacc[t] = __builtin_amdgcn_mfma_f32_16x16x32_bf16(qf[kc], kf, Sacc[t], 0, 0, 0);
      }
    }

    // ---- z = (S + bias) * SCALE  (C/D: row = lg*4+j, col = t*16+lr) ----
    float z[4][4];
    const int qr = qbase + lg * 4;
#pragma unroll
    for (int t = 0; t < 4; ++t) {
      const int kcol = kvbase + t * 16 + lr;
#pragma unroll
      for (int j = 0; j < 4; ++j)
        z[t][j] = (Sacc[t][j] + bias[(size_t)(qr + j) * L_ + kcol]) * SCALE;
    }
    if (b == 0) {
#pragma unroll
      for (int t = 0; t < 4; ++t) {
        const int kcol = kvbase + t * 16 + lr;
#pragma unroll
        for (int j = 0; j < 4; ++j)
          attn0[(size_t)(qr + j) * L_ + kcol] = z[t][j];
      }
    }

    // ---- online softmax ----
    float mt[4], corr[4], rs[4];
#pragma unroll
    for (int j = 0; j < 4; ++j) {
      float mm = fmaxf(fmaxf(z[0][j], z[1][j]), fmaxf(z[2][j], z[3][j]));
#pragma unroll
      for (int msk = 1; msk < 16; msk <<= 1) mm = fmaxf(mm, __shfl_xor(mm, msk));
      mt[j] = mm;
    }
#pragma unroll
    for (int j = 0; j < 4; ++j) {
      const float mnew = fmaxf(m_run[j], mt[j]);
      corr[j]  = exp2f((m_run[j] - mnew) * LOG2E);
      m_run[j] = mnew;
      rs[j]    = 0.f;
    }
    __bf16 pb[4][4];
#pragma unroll
    for (int t = 0; t < 4; ++t)
#pragma unroll
      for (int j = 0; j < 4; ++j) {
        const float p = exp2f((z[t][j] - m_run[j]) * LOG2E);
        rs[j] += p;
        pb[t][j] = (__bf16)p;
      }
#pragma unroll
    for (int j = 0; j < 4; ++j) {
      float s = rs[j];
#pragma unroll
      for (int msk = 1; msk < 16; msk <<= 1) s += __shfl_xor(s, msk);
      l_run[j] = l_run[j] * corr[j] + s;
    }
#pragma unroll
    for (int dt = 0; dt < 8; ++dt)
#pragma unroll
      for (int j = 0; j < 4; ++j) Oacc[dt][j] *= corr[j];

    // ---- P -> per-wave LDS (XOR-swizzled, stride 64) ----
    __bf16* pw = &Psh[wave][0];
    {
      const int m = lg * 4;
#pragma unroll
      for (int j = 0; j < 4; ++j) {
        const int s = lg << 4;  // ((m+j)>>2)&3 == lg
#pragma unroll
        for (int t = 0; t < 4; ++t) {
          const int c = t * 16 + lr;
          pw[(m + j) * 64 + (c ^ s)] = pb[t][j];
        }
      }
    }

    // ---- O += P . V ----
#pragma unroll
    for (int kc2 = 0; kc2 < 2; ++kc2) {
      const int c0  = kc2 * 32 + lg * 8;
      const int rs2 = ((lr >> 2) & 3) << 4;
      bf16x8 pa = *(const bf16x8*)(pw + lr * 64 + (c0 ^ rs2));
#pragma unroll
      for (int dt = 0; dt < 8; ++dt) {
        const int d = dt * 16 + lr;
        bf16x8 vf = *(const bf16x8*)(vb + d * 128 + ((c0 * 2) ^ ((d & 7) << 4)));
        Oacc[dt] = __builtin_amdgcn_mfma_f32_16x16x32_bf16(pa, vf, Oacc[dt], 0, 0, 0);
      }
    }

    __syncthreads();
    if constexpr (DMA) {
      if (kt + 2 < NT_) stage_dma(kt + 2, cur);
    }
  }

  // ---- epilogue: ctx = O / l ----
  float inv[4];
#pragma unroll
  for (int j = 0; j < 4; ++j) inv[j] = 1.f / l_run[j];
#pragma unroll
  for (int dt = 0; dt < 8; ++dt) {
    const int d = dt * 16 + lr;
#pragma unroll
    for (int j = 0; j < 4; ++j) {
      const int q = qbase + lg * 4 + j;
      ctx[((size_t)b * L_ + q) * D_ + d] = Oacc[dt][j] * inv[j];
    }
  }
}

// ---------------------------------------------------------------------------
// softmax_rows: in-place row softmax of attn0 (batch-0 raw scaled scores).
// ---------------------------------------------------------------------------
__global__ __launch_bounds__(256) void softmax_rows(float* __restrict__ attn0)
{
  const int row  = blockIdx.x;
  float* p = attn0 + (size_t)row * L_;
  const int tid  = threadIdx.x;
  const int wave = tid >> 6;
  const int lane = tid & 63;
  __shared__ float red[8];

  float4 a = ((const float4*)p)[tid];
  float4 c = ((const float4*)p)[tid + 256];
  float v[8] = {a.x, a.y, a.z, a.w, c.x, c.y, c.z, c.w};

  float mx = v[0];
#pragma unroll
  for (int i = 1; i < 8; ++i) mx = fmaxf(mx, v[i]);
#pragma unroll
  for (int msk = 1; msk < 64; msk <<= 1) mx = fmaxf(mx, __shfl_xor(mx, msk));
  if (lane == 0) red[wave] = mx;
  __syncthreads();
  mx = fmaxf(fmaxf(red[0], red[1]), fmaxf(red[2], red[3]));

  float e[8];
  float s = 0.f;
#pragma unroll
  for (int i = 0; i < 8; ++i) { e[i] = exp2f((v[i] - mx) * LOG2E); s += e[i]; }
#pragma unroll
  for (int msk = 1; msk < 64; msk <<= 1) s += __shfl_xor(s, msk);
  if (lane == 0) red[4 + wave] = s;
  __syncthreads();
  s = red[4] + red[5] + red[6] + red[7];
  const float inv = 1.f / s;

  float4 o0 = {e[0] * inv, e[1] * inv, e[2] * inv, e[3] * inv};
  float4 o1 = {e[4] * inv, e[5] * inv, e[6] * inv, e[7] * inv};
  ((float4*)p)[tid]       = o0;
  ((float4*)p)[tid + 256] = o1;
}

extern "C" void kernel_launch(void* const* d_in, const int* in_sizes, int n_in,
                              void* d_out, int out_size, void* d_ws, size_t ws_size,
                              hipStream_t stream) {
  const float* Q    = (const float*)d_in[0];
  const float* K    = (const float*)d_in[1];
  const float* V    = (const float*)d_in[2];
  const float* bias = (const float*)d_in[3];
  float* ctx   = (float*)d_out;
  float* attn0 = ctx + (size_t)B_ * L_ * D_;

  const size_t need = (size_t)2 * B_ * L_ * D_ * sizeof(__bf16);  // 33.6 MB
  if (ws_size >= need) {
    __bf16* gK  = (__bf16*)d_ws;
    __bf16* gVt = gK + (size_t)B_ * L_ * D_;
    prep_kv<<<dim3(B_ * NT_), 256, 0, stream>>>(K, V, gK, gVt);
    attn_fwd<1><<<dim3(B_ * NT_), 256, 0, stream>>>(Q, K, V, bias, gK, gVt, ctx, attn0);
  } else {
    attn_fwd<0><<<dim3(B_ * NT_), 256, 0, stream>>>(Q, K, V, bias, nullptr, nullptr, ctx, attn0);
  }
  softmax_rows<<<L_, 256, 0, stream>>>(attn0);
}